// Round 5
// baseline (383.222 us; speedup 1.0000x reference)
//
#include <hip/hip_runtime.h>

// GCN 2-layer + edge dot decoder. Dims fixed: in=512, hid=128, out=64.
#define IN_C  512
#define HID_C 128
#define OUT_C 64

using short8 = __attribute__((ext_vector_type(8))) short;   // 8 bf16
using floatx4 = __attribute__((ext_vector_type(4))) float;  // mfma acc

__device__ inline unsigned short f2bf(float f) {  // RNE
    unsigned u = __builtin_bit_cast(unsigned, f);
    u += 0x7FFFu + ((u >> 16) & 1u);
    return (unsigned short)(u >> 16);
}
__device__ inline float bf2f(unsigned short h) {
    unsigned u = ((unsigned)h) << 16;
    return __builtin_bit_cast(float, u);
}
__device__ inline unsigned short f2h(float f) {  // fp32 -> fp16 RNE
    _Float16 h = (_Float16)f;
    return __builtin_bit_cast(unsigned short, h);
}
__device__ inline float h2f(unsigned v) {  // low 16 bits = fp16
    return (float)__builtin_bit_cast(_Float16, (unsigned short)v);
}

// ---------------- CSR build ----------------
__global__ void k_zero_int(int* __restrict__ p, int n) {
    int i = blockIdx.x * blockDim.x + threadIdx.x;
    if (i < n) p[i] = 0;
}

__global__ void k_count(const int* __restrict__ dst, int* __restrict__ cnt, int e) {
    int i = blockIdx.x * blockDim.x + threadIdx.x;
    if (i < e) atomicAdd(&cnt[dst[i]], 1);
}

// block-sum of cnt + dinv computed in the same pass (cnt is final here)
__global__ void k_blocksum_dinv(const int* __restrict__ cnt, int* __restrict__ bsum,
                                float* __restrict__ dinv, int n) {
    __shared__ int sdata[256];
    int t = threadIdx.x;
    int i = blockIdx.x * 256 + t;
    int c = (i < n) ? cnt[i] : 0;
    if (i < n) dinv[i] = rsqrtf(1.0f + (float)c);  // +1 self-loop
    sdata[t] = c;
    __syncthreads();
    for (int s = 128; s > 0; s >>= 1) {
        if (t < s) sdata[t] += sdata[t + s];
        __syncthreads();
    }
    if (t == 0) bsum[blockIdx.x] = sdata[0];
}

__global__ void k_scanpartials(int* __restrict__ bsum, int nb) {
    __shared__ int sdata[256];
    int t = threadIdx.x;
    int orig = (t < nb) ? bsum[t] : 0;
    sdata[t] = orig;
    __syncthreads();
    for (int off = 1; off < 256; off <<= 1) {
        int v = (t >= off) ? sdata[t - off] : 0;
        __syncthreads();
        sdata[t] += v;
        __syncthreads();
    }
    if (t < nb) bsum[t] = sdata[t] - orig;  // exclusive
}

__global__ void k_scanfinal(const int* __restrict__ cnt, const int* __restrict__ bsum_ex,
                            int* __restrict__ row_ptr, int n, int e_total) {
    __shared__ int sdata[256];
    int t = threadIdx.x;
    int i = blockIdx.x * 256 + t;
    int orig = (i < n) ? cnt[i] : 0;
    sdata[t] = orig;
    __syncthreads();
    for (int off = 1; off < 256; off <<= 1) {
        int v = (t >= off) ? sdata[t - off] : 0;
        __syncthreads();
        sdata[t] += v;
        __syncthreads();
    }
    if (i < n) row_ptr[i] = sdata[t] - orig + bsum_ex[blockIdx.x];
    if (i == 0) row_ptr[n] = e_total;
}

// destructive fill: consumes cnt as a down-counter (cnt no longer needed after)
__global__ void k_fill(const int* __restrict__ src, const int* __restrict__ dst,
                       const int* __restrict__ row_ptr, int* __restrict__ cnt,
                       int* __restrict__ col, int e) {
    int i = blockIdx.x * blockDim.x + threadIdx.x;
    if (i < e) {
        int d = dst[i];
        int pos = atomicSub(&cnt[d], 1) - 1;  // unique slot in [0, deg)
        col[row_ptr[d] + pos] = src[i];
    }
}

// ---------------- weight prep (both layers in one launch) ----------------
// W [K][N] fp32 -> Wt_hi/Wt_lo [N][K] bf16 split
__global__ void k_prep_w2(const float* __restrict__ W1, unsigned short* __restrict__ hi1,
                          unsigned short* __restrict__ lo1, const float* __restrict__ W2,
                          unsigned short* __restrict__ hi2, unsigned short* __restrict__ lo2) {
    int i = blockIdx.x * blockDim.x + threadIdx.x;
    if (i < IN_C * HID_C) {
        int k = i / HID_C, n = i % HID_C;
        float v = W1[i];
        unsigned short h = f2bf(v);
        hi1[(long)n * IN_C + k] = h;
        lo1[(long)n * IN_C + k] = f2bf(v - bf2f(h));
    } else if (i < IN_C * HID_C + HID_C * OUT_C) {
        int j = i - IN_C * HID_C;
        int k = j / OUT_C, n = j % OUT_C;
        float v = W2[j];
        unsigned short h = f2bf(v);
        hi2[(long)n * HID_C + k] = h;
        lo2[(long)n * HID_C + k] = f2bf(v - bf2f(h));
    }
}

// ---------------- split-bf16 MFMA GEMM ----------------
// R4 A-path (register-prefetch + LDS double-buffer, proven) PLUS register-double-
// buffered B: tile t+2's B fragments are loaded right after tile t's compute consumes
// the set (~2 tile-times of L2-latency budget), so no B load sits in the MFMA chain.
// Loop is 2x unrolled so both B sets have static names (no scratch).
// K-summation order identical to before -> bitwise-identical numerics.
template <int K, int NPW>
__global__ __launch_bounds__(256) void k_gemm_mfma(
    const float* __restrict__ A, const unsigned short* __restrict__ Bt_hi,
    const unsigned short* __restrict__ Bt_lo, const float* __restrict__ dinv,
    unsigned short* __restrict__ Hs, int M) {
    constexpr int N = 64 * NPW;
    constexpr int LDA = 72;       // shorts; 144 B rows: frag b128 reads land 2-way (free)
    constexpr int NT = K / 64;    // number of 64-k tiles (8 or 2 -> even)
    static_assert((NT & 1) == 0, "NT must be even");
    __shared__ __align__(16) unsigned short As_hi[2][64 * LDA];
    __shared__ __align__(16) unsigned short As_lo[2][64 * LDA];

    const int tid = threadIdx.x;
    const int w = tid >> 6;
    const int lane = tid & 63;
    const int m = lane & 15;
    const int quad = lane >> 4;
    const int m0 = blockIdx.x * 64;

    // staging coords: thread handles rows srow+16i, fixed 4-float column skk
    const int srow = tid >> 4;
    const int skk = (tid & 15) << 2;

    floatx4 acc[4][NPW];
#pragma unroll
    for (int mi = 0; mi < 4; ++mi)
#pragma unroll
        for (int ni = 0; ni < NPW; ++ni) acc[mi][ni] = (floatx4){0.f, 0.f, 0.f, 0.f};

    float4 pf[4];
    short8 b0h[2][NPW], b0l[2][NPW], b1h[2][NPW], b1l[2][NPW];

    auto issueA = [&](int t0) {
#pragma unroll
        for (int i = 0; i < 4; ++i) {
            int gm = m0 + srow + 16 * i;
            pf[i] = make_float4(0.f, 0.f, 0.f, 0.f);
            if (gm < M) pf[i] = *(const float4*)&A[(long)gm * K + t0 * 64 + skk];
        }
    };
    auto convA = [&](int b) {
#pragma unroll
        for (int i = 0; i < 4; ++i) {
            ushort4 h, l;
            h.x = f2bf(pf[i].x); l.x = f2bf(pf[i].x - bf2f(h.x));
            h.y = f2bf(pf[i].y); l.y = f2bf(pf[i].y - bf2f(h.y));
            h.z = f2bf(pf[i].z); l.z = f2bf(pf[i].z - bf2f(h.z));
            h.w = f2bf(pf[i].w); l.w = f2bf(pf[i].w - bf2f(h.w));
            int off = (srow + 16 * i) * LDA + skk;
            *(ushort4*)&As_hi[b][off] = h;
            *(ushort4*)&As_lo[b][off] = l;
        }
    };
    auto loadB = [&](short8 bh[2][NPW], short8 bl[2][NPW], int t0) {
        if (t0 >= NT) return;
#pragma unroll
        for (int s = 0; s < 2; ++s)
#pragma unroll
            for (int ni = 0; ni < NPW; ++ni) {
                int n = (w * NPW + ni) * 16 + m;
                long boff = (long)n * K + t0 * 64 + s * 32 + quad * 8;
                bh[s][ni] = *(const short8*)&Bt_hi[boff];
                bl[s][ni] = *(const short8*)&Bt_lo[boff];
            }
    };
    auto compute = [&](int b, short8 bh[2][NPW], short8 bl[2][NPW]) {
#pragma unroll
        for (int s = 0; s < 2; ++s) {
            short8 ah[4], al[4];
#pragma unroll
            for (int mi = 0; mi < 4; ++mi) {
                int off = (mi * 16 + m) * LDA + s * 32 + quad * 8;
                ah[mi] = *(const short8*)&As_hi[b][off];
                al[mi] = *(const short8*)&As_lo[b][off];
            }
#pragma unroll
            for (int ni = 0; ni < NPW; ++ni) {
#pragma unroll
                for (int mi = 0; mi < 4; ++mi) {
                    acc[mi][ni] = __builtin_amdgcn_mfma_f32_16x16x32_bf16(ah[mi], bh[s][ni], acc[mi][ni], 0, 0, 0);
                    acc[mi][ni] = __builtin_amdgcn_mfma_f32_16x16x32_bf16(ah[mi], bl[s][ni], acc[mi][ni], 0, 0, 0);
                    acc[mi][ni] = __builtin_amdgcn_mfma_f32_16x16x32_bf16(al[mi], bh[s][ni], acc[mi][ni], 0, 0, 0);
                }
            }
        }
    };

    // prologue: A tile 0 -> buf0; B tiles 0,1 -> regs
    issueA(0);
    loadB(b0h, b0l, 0);
    loadB(b1h, b1l, 1);
    convA(0);

#pragma unroll
    for (int t = 0; t < NT; t += 2) {
        __syncthreads();                 // buf0 holds tile t
        issueA(t + 1);                   // A prefetch (depth 1, as R4)
        compute(0, b0h, b0l);
        loadB(b0h, b0l, t + 2);          // refill even B set (2-tile budget)
        convA(1);                        // A(t+1) -> buf1
        __syncthreads();                 // buf1 holds tile t+1
        if (t + 2 < NT) issueA(t + 2);
        compute(1, b1h, b1l);
        loadB(b1h, b1l, t + 3);          // refill odd B set
        if (t + 2 < NT) convA(0);        // A(t+2) -> buf0
    }

    // epilogue: C/D layout col=lane&15, row=quad*4+reg; scale by dinv[row]; fp16 store
#pragma unroll
    for (int mi = 0; mi < 4; ++mi) {
#pragma unroll
        for (int r = 0; r < 4; ++r) {
            int row = m0 + mi * 16 + quad * 4 + r;
            if (row < M) {
                float dv = dinv[row];
#pragma unroll
                for (int ni = 0; ni < NPW; ++ni) {
                    int n = (w * NPW + ni) * 16 + m;
                    Hs[(long)row * N + n] = f2h(acc[mi][ni][r] * dv);
                }
            }
        }
    }
}

// ---------------- CSR aggregation, wave per node, half-wave edge pairing ----------------
__global__ __launch_bounds__(256) void k_agg1(
    const unsigned short* __restrict__ h, const int* __restrict__ row_ptr,
    const int* __restrict__ col, const float* __restrict__ dinv,
    const float* __restrict__ bias, float* __restrict__ z, int n) {
    int node = blockIdx.x * 4 + (threadIdx.x >> 6);
    node = __builtin_amdgcn_readfirstlane(node);
    if (node >= n) return;
    int lane = threadIdx.x & 63;
    int half = lane >> 5, li = lane & 31;
    const uint2* hp = (const uint2*)h;  // 32 uint2 per row (128 ch fp16)
    float4 acc = make_float4(0.f, 0.f, 0.f, 0.f);
    if (half == 0) {  // self-loop counted once
        uint2 v = hp[(long)node * 32 + li];
        acc.x = h2f(v.x); acc.y = h2f(v.x >> 16);
        acc.z = h2f(v.y); acc.w = h2f(v.y >> 16);
    }
    int rs = row_ptr[node], re = row_ptr[node + 1];
    int cnt = re - rs, pairs = cnt >> 1;
    int j = rs + half;
    int p = 0;
    for (; p + 4 <= pairs; p += 4, j += 8) {
        int s0 = col[j], s1 = col[j + 2], s2 = col[j + 4], s3 = col[j + 6];
        uint2 v0 = hp[(long)s0 * 32 + li];
        uint2 v1 = hp[(long)s1 * 32 + li];
        uint2 v2 = hp[(long)s2 * 32 + li];
        uint2 v3 = hp[(long)s3 * 32 + li];
        acc.x += h2f(v0.x) + h2f(v1.x) + h2f(v2.x) + h2f(v3.x);
        acc.y += h2f(v0.x >> 16) + h2f(v1.x >> 16) + h2f(v2.x >> 16) + h2f(v3.x >> 16);
        acc.z += h2f(v0.y) + h2f(v1.y) + h2f(v2.y) + h2f(v3.y);
        acc.w += h2f(v0.y >> 16) + h2f(v1.y >> 16) + h2f(v2.y >> 16) + h2f(v3.y >> 16);
    }
    for (; p < pairs; ++p, j += 2) {
        int s = col[j];
        uint2 v = hp[(long)s * 32 + li];
        acc.x += h2f(v.x); acc.y += h2f(v.x >> 16);
        acc.z += h2f(v.y); acc.w += h2f(v.y >> 16);
    }
    if ((cnt & 1) && half == 0) {  // odd tail handled by low half
        int s = col[re - 1];
        uint2 v = hp[(long)s * 32 + li];
        acc.x += h2f(v.x); acc.y += h2f(v.x >> 16);
        acc.z += h2f(v.y); acc.w += h2f(v.y >> 16);
    }
    // combine halves
    float ox = __shfl(acc.x, li + 32);
    float oy = __shfl(acc.y, li + 32);
    float oz = __shfl(acc.z, li + 32);
    float ow = __shfl(acc.w, li + 32);
    if (half == 0) {
        acc.x += ox; acc.y += oy; acc.z += oz; acc.w += ow;
        float dv = dinv[node];
        float4 b = ((const float4*)bias)[li];
        float4 o;
        o.x = fmaxf(fmaf(acc.x, dv, b.x), 0.f);
        o.y = fmaxf(fmaf(acc.y, dv, b.y), 0.f);
        o.z = fmaxf(fmaf(acc.z, dv, b.z), 0.f);
        o.w = fmaxf(fmaf(acc.w, dv, b.w), 0.f);
        ((float4*)z)[(long)node * 32 + li] = o;
    }
}

__global__ __launch_bounds__(256) void k_agg2(
    const unsigned short* __restrict__ h, const int* __restrict__ row_ptr,
    const int* __restrict__ col, const float* __restrict__ dinv,
    const float* __restrict__ bias, float* __restrict__ z, int n) {
    int node = blockIdx.x * 4 + (threadIdx.x >> 6);
    node = __builtin_amdgcn_readfirstlane(node);
    if (node >= n) return;
    int lane = threadIdx.x & 63;
    int half = lane >> 5, li = lane & 31;
    const unsigned* hp = (const unsigned*)h;  // 32 uints per row (64 ch fp16)
    float2 acc = make_float2(0.f, 0.f);
    if (half == 0) {  // self-loop
        unsigned v = hp[(long)node * 32 + li];
        acc.x = h2f(v); acc.y = h2f(v >> 16);
    }
    int rs = row_ptr[node], re = row_ptr[node + 1];
    int cnt = re - rs, pairs = cnt >> 1;
    int j = rs + half;
    int p = 0;
    for (; p + 4 <= pairs; p += 4, j += 8) {
        int s0 = col[j], s1 = col[j + 2], s2 = col[j + 4], s3 = col[j + 6];
        unsigned v0 = hp[(long)s0 * 32 + li];
        unsigned v1 = hp[(long)s1 * 32 + li];
        unsigned v2 = hp[(long)s2 * 32 + li];
        unsigned v3 = hp[(long)s3 * 32 + li];
        acc.x += h2f(v0) + h2f(v1) + h2f(v2) + h2f(v3);
        acc.y += h2f(v0 >> 16) + h2f(v1 >> 16) + h2f(v2 >> 16) + h2f(v3 >> 16);
    }
    for (; p < pairs; ++p, j += 2) {
        unsigned v = hp[(long)col[j] * 32 + li];
        acc.x += h2f(v); acc.y += h2f(v >> 16);
    }
    if ((cnt & 1) && half == 0) {
        unsigned v = hp[(long)col[re - 1] * 32 + li];
        acc.x += h2f(v); acc.y += h2f(v >> 16);
    }
    float ox = __shfl(acc.x, li + 32);
    float oy = __shfl(acc.y, li + 32);
    if (half == 0) {
        acc.x += ox; acc.y += oy;
        float dv = dinv[node];
        float2 b = ((const float2*)bias)[li];
        float2 o;
        o.x = fmaf(acc.x, dv, b.x);
        o.y = fmaf(acc.y, dv, b.y);
        ((float2*)z)[(long)node * 32 + li] = o;
    }
}

// ---------------- decoder: 2 edges per wave (half-wave each, float2 per lane) ----------
__global__ void k_dot(const float* __restrict__ z2, const int* __restrict__ es,
                      const int* __restrict__ ed, float* __restrict__ out, int L) {
    int gid = blockIdx.x * blockDim.x + threadIdx.x;
    int wid = gid >> 6;
    int lane = threadIdx.x & 63;
    int half = lane >> 5, li = lane & 31;
    int e = wid * 2 + half;
    if (e >= L) return;
    int a = es[e], b = ed[e];
    const float2* zp = (const float2*)z2;
    float2 za = zp[(long)a * 32 + li];
    float2 zb = zp[(long)b * 32 + li];
    float v = za.x * zb.x + za.y * zb.y;
#pragma unroll
    for (int off = 16; off > 0; off >>= 1) v += __shfl_down(v, off);  // within half
    if (li == 0) out[e] = v;
}

extern "C" void kernel_launch(void* const* d_in, const int* in_sizes, int n_in,
                              void* d_out, int out_size, void* d_ws, size_t ws_size,
                              hipStream_t stream) {
    const float* x = (const float*)d_in[0];
    const int* ei = (const int*)d_in[1];
    const int* eli = (const int*)d_in[2];
    const float* W1 = (const float*)d_in[3];
    const float* b1 = (const float*)d_in[4];
    const float* W2 = (const float*)d_in[5];
    const float* b2 = (const float*)d_in[6];
    float* out = (float*)d_out;

    const int N = in_sizes[0] / IN_C;  // 50000
    const int E = in_sizes[1] / 2;     // 800000
    const int L = in_sizes[2] / 2;     // 100000
    const int* src = ei;
    const int* dst = ei + E;
    const int* es = eli;
    const int* ed = eli + L;

    const int Npad = (N + 63) & ~63;
    const int Epad = (E + 3) & ~3;

    // workspace layout
    int* cnt = (int*)d_ws;             // Npad (also the fill cursor, consumed)
    int* row_ptr = cnt + Npad;         // Npad + 64
    int* bsum = row_ptr + Npad + 64;   // 256
    int* col = bsum + 256;             // Epad
    float* dinv = (float*)(col + Epad);                   // Npad
    unsigned short* h1s = (unsigned short*)(dinv + Npad); // N*128 fp16 (16B-aligned)
    float* z1 = (float*)(h1s + (long)N * HID_C);          // N*128 fp32
    unsigned short* h2s = h1s;                            // alias: h1s dead after agg1
    float* z2 = z1 + (long)N * HID_C;                     // N*64 fp32
    unsigned short* wt1_hi = (unsigned short*)(z2 + (long)N * OUT_C);  // 512*128
    unsigned short* wt1_lo = wt1_hi + IN_C * HID_C;
    unsigned short* wt2_hi = wt1_lo + IN_C * HID_C;                    // 128*64
    unsigned short* wt2_lo = wt2_hi + HID_C * OUT_C;

    const int TPB = 256;
    const int nb = (N + 255) / 256;

    // weight prep (both layers, one launch)
    const int PW = IN_C * HID_C + HID_C * OUT_C;
    k_prep_w2<<<(PW + TPB - 1) / TPB, TPB, 0, stream>>>(W1, wt1_hi, wt1_lo, W2, wt2_hi, wt2_lo);

    // CSR build + dinv
    k_zero_int<<<(Npad + TPB - 1) / TPB, TPB, 0, stream>>>(cnt, Npad);
    k_count<<<(E + TPB - 1) / TPB, TPB, 0, stream>>>(dst, cnt, E);
    k_blocksum_dinv<<<nb, 256, 0, stream>>>(cnt, bsum, dinv, N);
    k_scanpartials<<<1, 256, 0, stream>>>(bsum, nb);
    k_scanfinal<<<nb, 256, 0, stream>>>(cnt, bsum, row_ptr, N, E);
    k_fill<<<(E + TPB - 1) / TPB, TPB, 0, stream>>>(src, dst, row_ptr, cnt, col, E);

    // layer 1
    k_gemm_mfma<IN_C, 2><<<(N + 63) / 64, 256, 0, stream>>>(x, wt1_hi, wt1_lo, dinv, h1s, N);
    k_agg1<<<(N + 3) / 4, 256, 0, stream>>>(h1s, row_ptr, col, dinv, b1, z1, N);

    // layer 2
    k_gemm_mfma<HID_C, 1><<<(N + 63) / 64, 256, 0, stream>>>(z1, wt2_hi, wt2_lo, dinv, h2s, N);
    k_agg2<<<(N + 3) / 4, 256, 0, stream>>>(h2s, row_ptr, col, dinv, b2, z2, N);

    // decoder (2 edges/wave)
    k_dot<<<((long)((L + 1) / 2) * 64 + TPB - 1) / TPB, TPB, 0, stream>>>(z2, es, ed, out, L);
}

// Round 6
// 367.566 us; speedup vs baseline: 1.0426x; 1.0426x over previous
//
#include <hip/hip_runtime.h>

// GCN 2-layer + edge dot decoder. Dims fixed: in=512, hid=128, out=64.
#define IN_C  512
#define HID_C 128
#define OUT_C 64

using short8 = __attribute__((ext_vector_type(8))) short;   // 8 bf16
using floatx4 = __attribute__((ext_vector_type(4))) float;  // mfma acc

__device__ inline unsigned short f2bf(float f) {  // RNE
    unsigned u = __builtin_bit_cast(unsigned, f);
    u += 0x7FFFu + ((u >> 16) & 1u);
    return (unsigned short)(u >> 16);
}
__device__ inline float bf2f(unsigned short h) {
    unsigned u = ((unsigned)h) << 16;
    return __builtin_bit_cast(float, u);
}
__device__ inline unsigned short f2h(float f) {  // fp32 -> fp16 RNE
    _Float16 h = (_Float16)f;
    return __builtin_bit_cast(unsigned short, h);
}
__device__ inline float h2f(unsigned v) {  // low 16 bits = fp16
    return (float)__builtin_bit_cast(_Float16, (unsigned short)v);
}

// ---------------- CSR build ----------------
__global__ void k_zero_int(int* __restrict__ p, int n) {
    int i = blockIdx.x * blockDim.x + threadIdx.x;
    if (i < n) p[i] = 0;
}

__global__ void k_count(const int* __restrict__ dst, int* __restrict__ cnt, int e) {
    int i = blockIdx.x * blockDim.x + threadIdx.x;
    if (i < e) atomicAdd(&cnt[dst[i]], 1);
}

// block-sum of cnt + dinv computed in the same pass (cnt is final here)
__global__ void k_blocksum_dinv(const int* __restrict__ cnt, int* __restrict__ bsum,
                                float* __restrict__ dinv, int n) {
    __shared__ int sdata[256];
    int t = threadIdx.x;
    int i = blockIdx.x * 256 + t;
    int c = (i < n) ? cnt[i] : 0;
    if (i < n) dinv[i] = rsqrtf(1.0f + (float)c);  // +1 self-loop
    sdata[t] = c;
    __syncthreads();
    for (int s = 128; s > 0; s >>= 1) {
        if (t < s) sdata[t] += sdata[t + s];
        __syncthreads();
    }
    if (t == 0) bsum[blockIdx.x] = sdata[0];
}

__global__ void k_scanpartials(int* __restrict__ bsum, int nb) {
    __shared__ int sdata[256];
    int t = threadIdx.x;
    int orig = (t < nb) ? bsum[t] : 0;
    sdata[t] = orig;
    __syncthreads();
    for (int off = 1; off < 256; off <<= 1) {
        int v = (t >= off) ? sdata[t - off] : 0;
        __syncthreads();
        sdata[t] += v;
        __syncthreads();
    }
    if (t < nb) bsum[t] = sdata[t] - orig;  // exclusive
}

__global__ void k_scanfinal(const int* __restrict__ cnt, const int* __restrict__ bsum_ex,
                            int* __restrict__ row_ptr, int n, int e_total) {
    __shared__ int sdata[256];
    int t = threadIdx.x;
    int i = blockIdx.x * 256 + t;
    int orig = (i < n) ? cnt[i] : 0;
    sdata[t] = orig;
    __syncthreads();
    for (int off = 1; off < 256; off <<= 1) {
        int v = (t >= off) ? sdata[t - off] : 0;
        __syncthreads();
        sdata[t] += v;
        __syncthreads();
    }
    if (i < n) row_ptr[i] = sdata[t] - orig + bsum_ex[blockIdx.x];
    if (i == 0) row_ptr[n] = e_total;
}

// destructive fill: consumes cnt as a down-counter (cnt no longer needed after)
__global__ void k_fill(const int* __restrict__ src, const int* __restrict__ dst,
                       const int* __restrict__ row_ptr, int* __restrict__ cnt,
                       int* __restrict__ col, int e) {
    int i = blockIdx.x * blockDim.x + threadIdx.x;
    if (i < e) {
        int d = dst[i];
        int pos = atomicSub(&cnt[d], 1) - 1;  // unique slot in [0, deg)
        col[row_ptr[d] + pos] = src[i];
    }
}

// ---------------- weight prep (both layers in one launch) ----------------
__global__ void k_prep_w2(const float* __restrict__ W1, unsigned short* __restrict__ hi1,
                          unsigned short* __restrict__ lo1, const float* __restrict__ W2,
                          unsigned short* __restrict__ hi2, unsigned short* __restrict__ lo2) {
    int i = blockIdx.x * blockDim.x + threadIdx.x;
    if (i < IN_C * HID_C) {
        int k = i / HID_C, n = i % HID_C;
        float v = W1[i];
        unsigned short h = f2bf(v);
        hi1[(long)n * IN_C + k] = h;
        lo1[(long)n * IN_C + k] = f2bf(v - bf2f(h));
    } else if (i < IN_C * HID_C + HID_C * OUT_C) {
        int j = i - IN_C * HID_C;
        int k = j / OUT_C, n = j % OUT_C;
        float v = W2[j];
        unsigned short h = f2bf(v);
        hi2[(long)n * HID_C + k] = h;
        lo2[(long)n * HID_C + k] = f2bf(v - bf2f(h));
    }
}

// ---------------- split-bf16 MFMA GEMM (R4 structure — best measured, 73 us) --------
// Register-prefetch + LDS double-buffer, one __syncthreads per 64-k tile.
// Five structural variants (BM=32, no-LDS direct, depth-2+raw-barrier, B-reg dbuf)
// all landed 73-86 us with identical counters -> this kernel sits at a memory-system
// floor for its access pattern; do not restructure further.
template <int K, int NPW>
__global__ __launch_bounds__(256) void k_gemm_mfma(
    const float* __restrict__ A, const unsigned short* __restrict__ Bt_hi,
    const unsigned short* __restrict__ Bt_lo, const float* __restrict__ dinv,
    unsigned short* __restrict__ Hs, int M) {
    constexpr int N = 64 * NPW;
    constexpr int LDA = 72;       // shorts; 144 B rows: frag b128 reads land 2-way (free)
    constexpr int NT = K / 64;    // number of 64-k tiles
    __shared__ __align__(16) unsigned short As_hi[2][64 * LDA];
    __shared__ __align__(16) unsigned short As_lo[2][64 * LDA];

    const int tid = threadIdx.x;
    const int w = tid >> 6;
    const int lane = tid & 63;
    const int m = lane & 15;
    const int quad = lane >> 4;
    const int m0 = blockIdx.x * 64;

    // staging coords: thread handles rows srow+16i, fixed 4-float column skk
    const int srow = tid >> 4;
    const int skk = (tid & 15) << 2;

    floatx4 acc[4][NPW];
#pragma unroll
    for (int mi = 0; mi < 4; ++mi)
#pragma unroll
        for (int ni = 0; ni < NPW; ++ni) acc[mi][ni] = (floatx4){0.f, 0.f, 0.f, 0.f};

    float4 pf[4];
    // prologue: load + convert tile 0 into buf 0
#pragma unroll
    for (int i = 0; i < 4; ++i) {
        int gm = m0 + srow + 16 * i;
        pf[i] = make_float4(0.f, 0.f, 0.f, 0.f);
        if (gm < M) pf[i] = *(const float4*)&A[(long)gm * K + skk];
    }
#pragma unroll
    for (int i = 0; i < 4; ++i) {
        ushort4 h, l;
        h.x = f2bf(pf[i].x); l.x = f2bf(pf[i].x - bf2f(h.x));
        h.y = f2bf(pf[i].y); l.y = f2bf(pf[i].y - bf2f(h.y));
        h.z = f2bf(pf[i].z); l.z = f2bf(pf[i].z - bf2f(h.z));
        h.w = f2bf(pf[i].w); l.w = f2bf(pf[i].w - bf2f(h.w));
        int off = (srow + 16 * i) * LDA + skk;
        *(ushort4*)&As_hi[0][off] = h;
        *(ushort4*)&As_lo[0][off] = l;
    }

    for (int t = 0; t < NT; ++t) {
        __syncthreads();  // buf[t&1] fully written; prior readers of buf[(t+1)&1] done
        const int buf = t & 1;
        // prefetch next tile into registers (latency overlaps compute below)
        if (t + 1 < NT) {
#pragma unroll
            for (int i = 0; i < 4; ++i) {
                int gm = m0 + srow + 16 * i;
                pf[i] = make_float4(0.f, 0.f, 0.f, 0.f);
                if (gm < M) pf[i] = *(const float4*)&A[(long)gm * K + (t + 1) * 64 + skk];
            }
        }
        // compute from buf
#pragma unroll
        for (int s = 0; s < 2; ++s) {
            short8 ah[4], al[4];
#pragma unroll
            for (int mi = 0; mi < 4; ++mi) {
                int off = (mi * 16 + m) * LDA + s * 32 + quad * 8;
                ah[mi] = *(const short8*)&As_hi[buf][off];
                al[mi] = *(const short8*)&As_lo[buf][off];
            }
#pragma unroll
            for (int ni = 0; ni < NPW; ++ni) {
                int n = (w * NPW + ni) * 16 + m;
                long boff = (long)n * K + t * 64 + s * 32 + quad * 8;
                short8 bh = *(const short8*)&Bt_hi[boff];
                short8 bl = *(const short8*)&Bt_lo[boff];
#pragma unroll
                for (int mi = 0; mi < 4; ++mi) {
                    acc[mi][ni] = __builtin_amdgcn_mfma_f32_16x16x32_bf16(ah[mi], bh, acc[mi][ni], 0, 0, 0);
                    acc[mi][ni] = __builtin_amdgcn_mfma_f32_16x16x32_bf16(ah[mi], bl, acc[mi][ni], 0, 0, 0);
                    acc[mi][ni] = __builtin_amdgcn_mfma_f32_16x16x32_bf16(al[mi], bh, acc[mi][ni], 0, 0, 0);
                }
            }
        }
        // convert prefetched regs into the other buffer
        if (t + 1 < NT) {
#pragma unroll
            for (int i = 0; i < 4; ++i) {
                ushort4 h, l;
                h.x = f2bf(pf[i].x); l.x = f2bf(pf[i].x - bf2f(h.x));
                h.y = f2bf(pf[i].y); l.y = f2bf(pf[i].y - bf2f(h.y));
                h.z = f2bf(pf[i].z); l.z = f2bf(pf[i].z - bf2f(h.z));
                h.w = f2bf(pf[i].w); l.w = f2bf(pf[i].w - bf2f(h.w));
                int off = (srow + 16 * i) * LDA + skk;
                *(ushort4*)&As_hi[buf ^ 1][off] = h;
                *(ushort4*)&As_lo[buf ^ 1][off] = l;
            }
        }
    }

    // epilogue: C/D layout col=lane&15, row=quad*4+reg; scale by dinv[row]; fp16 store
#pragma unroll
    for (int mi = 0; mi < 4; ++mi) {
#pragma unroll
        for (int r = 0; r < 4; ++r) {
            int row = m0 + mi * 16 + quad * 4 + r;
            if (row < M) {
                float dv = dinv[row];
#pragma unroll
                for (int ni = 0; ni < NPW; ++ni) {
                    int n = (w * NPW + ni) * 16 + m;
                    Hs[(long)row * N + n] = f2h(acc[mi][ni][r] * dv);
                }
            }
        }
    }
}

// ---------------- CSR aggregation: quarter-wave gathers (4 edges in flight/wave) ------
// One node per wave. Each 16-lane quarter q processes edges j = rs+q, rs+q+4, ...
// (16 lanes x 16 B = one full 256 B row per gather). 4x unroll -> up to 16 outstanding
// gathers per wave (2x the half-wave scheme). Quarters combined via __shfl_xor(16,32);
// wave-uniform node guard keeps all 64 lanes converged at the reduction.
__global__ __launch_bounds__(256) void k_agg1(
    const unsigned short* __restrict__ h, const int* __restrict__ row_ptr,
    const int* __restrict__ col, const float* __restrict__ dinv,
    const float* __restrict__ bias, float* __restrict__ z, int n) {
    int node = blockIdx.x * 4 + (threadIdx.x >> 6);
    node = __builtin_amdgcn_readfirstlane(node);
    if (node >= n) return;
    int lane = threadIdx.x & 63;
    int q = lane >> 4, li = lane & 15;
    const uint4* hp = (const uint4*)h;  // 16 uint4 per row (128 ch fp16 = 256 B)
    float acc[8] = {0.f, 0.f, 0.f, 0.f, 0.f, 0.f, 0.f, 0.f};
    auto addrow = [&](uint4 v) {
        acc[0] += h2f(v.x); acc[1] += h2f(v.x >> 16);
        acc[2] += h2f(v.y); acc[3] += h2f(v.y >> 16);
        acc[4] += h2f(v.z); acc[5] += h2f(v.z >> 16);
        acc[6] += h2f(v.w); acc[7] += h2f(v.w >> 16);
    };
    if (q == 0) addrow(hp[(long)node * 16 + li]);  // self-loop once
    int rs = row_ptr[node], re = row_ptr[node + 1];
    int j = rs + q;
    for (; j + 12 < re; j += 16) {  // 4 gathers in flight per quarter
        int s0 = col[j], s1 = col[j + 4], s2 = col[j + 8], s3 = col[j + 12];
        uint4 v0 = hp[(long)s0 * 16 + li];
        uint4 v1 = hp[(long)s1 * 16 + li];
        uint4 v2 = hp[(long)s2 * 16 + li];
        uint4 v3 = hp[(long)s3 * 16 + li];
        addrow(v0); addrow(v1); addrow(v2); addrow(v3);
    }
    for (; j < re; j += 4) addrow(hp[(long)col[j] * 16 + li]);
    // combine quarters: lanes {li, li+16, li+32, li+48} hold partials of same channels
#pragma unroll
    for (int k = 0; k < 8; ++k) {
        acc[k] += __shfl_xor(acc[k], 16);
        acc[k] += __shfl_xor(acc[k], 32);
    }
    if (q == 0) {
        float dv = dinv[node];
        const float4* bp = (const float4*)bias;
        float4 b0 = bp[li * 2], b1 = bp[li * 2 + 1];
        float4 o0, o1;
        o0.x = fmaxf(fmaf(acc[0], dv, b0.x), 0.f);
        o0.y = fmaxf(fmaf(acc[1], dv, b0.y), 0.f);
        o0.z = fmaxf(fmaf(acc[2], dv, b0.z), 0.f);
        o0.w = fmaxf(fmaf(acc[3], dv, b0.w), 0.f);
        o1.x = fmaxf(fmaf(acc[4], dv, b1.x), 0.f);
        o1.y = fmaxf(fmaf(acc[5], dv, b1.y), 0.f);
        o1.z = fmaxf(fmaf(acc[6], dv, b1.z), 0.f);
        o1.w = fmaxf(fmaf(acc[7], dv, b1.w), 0.f);
        ((float4*)z)[(long)node * 32 + li * 2] = o0;
        ((float4*)z)[(long)node * 32 + li * 2 + 1] = o1;
    }
}

__global__ __launch_bounds__(256) void k_agg2(
    const unsigned short* __restrict__ h, const int* __restrict__ row_ptr,
    const int* __restrict__ col, const float* __restrict__ dinv,
    const float* __restrict__ bias, float* __restrict__ z, int n) {
    int node = blockIdx.x * 4 + (threadIdx.x >> 6);
    node = __builtin_amdgcn_readfirstlane(node);
    if (node >= n) return;
    int lane = threadIdx.x & 63;
    int q = lane >> 4, li = lane & 15;
    const uint2* hp = (const uint2*)h;  // 16 uint2 per row (64 ch fp16 = 128 B)
    float acc[4] = {0.f, 0.f, 0.f, 0.f};
    auto addrow = [&](uint2 v) {
        acc[0] += h2f(v.x); acc[1] += h2f(v.x >> 16);
        acc[2] += h2f(v.y); acc[3] += h2f(v.y >> 16);
    };
    if (q == 0) addrow(hp[(long)node * 16 + li]);  // self-loop
    int rs = row_ptr[node], re = row_ptr[node + 1];
    int j = rs + q;
    for (; j + 12 < re; j += 16) {
        int s0 = col[j], s1 = col[j + 4], s2 = col[j + 8], s3 = col[j + 12];
        uint2 v0 = hp[(long)s0 * 16 + li];
        uint2 v1 = hp[(long)s1 * 16 + li];
        uint2 v2 = hp[(long)s2 * 16 + li];
        uint2 v3 = hp[(long)s3 * 16 + li];
        addrow(v0); addrow(v1); addrow(v2); addrow(v3);
    }
    for (; j < re; j += 4) addrow(hp[(long)col[j] * 16 + li]);
#pragma unroll
    for (int k = 0; k < 4; ++k) {
        acc[k] += __shfl_xor(acc[k], 16);
        acc[k] += __shfl_xor(acc[k], 32);
    }
    if (q == 0) {
        float dv = dinv[node];
        float4 b = ((const float4*)bias)[li];
        float4 o;
        o.x = fmaf(acc[0], dv, b.x);
        o.y = fmaf(acc[1], dv, b.y);
        o.z = fmaf(acc[2], dv, b.z);
        o.w = fmaf(acc[3], dv, b.w);
        ((float4*)z)[(long)node * 16 + li] = o;
    }
}

// ---------------- decoder: 4 edges per wave (quarter-wave each, float4 per lane) ------
__global__ void k_dot(const float* __restrict__ z2, const int* __restrict__ es,
                      const int* __restrict__ ed, float* __restrict__ out, int L) {
    int gid = blockIdx.x * blockDim.x + threadIdx.x;
    int wid = gid >> 6;
    int lane = threadIdx.x & 63;
    int q = lane >> 4, li = lane & 15;
    int e = wid * 4 + q;
    if (e >= L) return;
    int a = es[e], b = ed[e];
    const float4* zp = (const float4*)z2;  // 16 float4 per row (64 ch fp32)
    float4 za = zp[(long)a * 16 + li];
    float4 zb = zp[(long)b * 16 + li];
    float v = za.x * zb.x + za.y * zb.y + za.z * zb.z + za.w * zb.w;
#pragma unroll
    for (int off = 8; off > 0; off >>= 1) v += __shfl_xor(v, off);  // within quarter
    if (li == 0) out[e] = v;
}

extern "C" void kernel_launch(void* const* d_in, const int* in_sizes, int n_in,
                              void* d_out, int out_size, void* d_ws, size_t ws_size,
                              hipStream_t stream) {
    const float* x = (const float*)d_in[0];
    const int* ei = (const int*)d_in[1];
    const int* eli = (const int*)d_in[2];
    const float* W1 = (const float*)d_in[3];
    const float* b1 = (const float*)d_in[4];
    const float* W2 = (const float*)d_in[5];
    const float* b2 = (const float*)d_in[6];
    float* out = (float*)d_out;

    const int N = in_sizes[0] / IN_C;  // 50000
    const int E = in_sizes[1] / 2;     // 800000
    const int L = in_sizes[2] / 2;     // 100000
    const int* src = ei;
    const int* dst = ei + E;
    const int* es = eli;
    const int* ed = eli + L;

    const int Npad = (N + 63) & ~63;
    const int Epad = (E + 3) & ~3;

    // workspace layout
    int* cnt = (int*)d_ws;             // Npad (also the fill cursor, consumed)
    int* row_ptr = cnt + Npad;         // Npad + 64
    int* bsum = row_ptr + Npad + 64;   // 256
    int* col = bsum + 256;             // Epad
    float* dinv = (float*)(col + Epad);                   // Npad
    unsigned short* h1s = (unsigned short*)(dinv + Npad); // N*128 fp16 (16B-aligned)
    float* z1 = (float*)(h1s + (long)N * HID_C);          // N*128 fp32
    unsigned short* h2s = h1s;                            // alias: h1s dead after agg1
    float* z2 = z1 + (long)N * HID_C;                     // N*64 fp32
    unsigned short* wt1_hi = (unsigned short*)(z2 + (long)N * OUT_C);  // 512*128
    unsigned short* wt1_lo = wt1_hi + IN_C * HID_C;
    unsigned short* wt2_hi = wt1_lo + IN_C * HID_C;                    // 128*64
    unsigned short* wt2_lo = wt2_hi + HID_C * OUT_C;

    const int TPB = 256;
    const int nb = (N + 255) / 256;

    // weight prep (both layers, one launch)
    const int PW = IN_C * HID_C + HID_C * OUT_C;
    k_prep_w2<<<(PW + TPB - 1) / TPB, TPB, 0, stream>>>(W1, wt1_hi, wt1_lo, W2, wt2_hi, wt2_lo);

    // CSR build + dinv
    k_zero_int<<<(Npad + TPB - 1) / TPB, TPB, 0, stream>>>(cnt, Npad);
    k_count<<<(E + TPB - 1) / TPB, TPB, 0, stream>>>(dst, cnt, E);
    k_blocksum_dinv<<<nb, 256, 0, stream>>>(cnt, bsum, dinv, N);
    k_scanpartials<<<1, 256, 0, stream>>>(bsum, nb);
    k_scanfinal<<<nb, 256, 0, stream>>>(cnt, bsum, row_ptr, N, E);
    k_fill<<<(E + TPB - 1) / TPB, TPB, 0, stream>>>(src, dst, row_ptr, cnt, col, E);

    // layer 1
    k_gemm_mfma<IN_C, 2><<<(N + 63) / 64, 256, 0, stream>>>(x, wt1_hi, wt1_lo, dinv, h1s, N);
    k_agg1<<<(N + 3) / 4, 256, 0, stream>>>(h1s, row_ptr, col, dinv, b1, z1, N);

    // layer 2
    k_gemm_mfma<HID_C, 1><<<(N + 63) / 64, 256, 0, stream>>>(z1, wt2_hi, wt2_lo, dinv, h2s, N);
    k_agg2<<<(N + 3) / 4, 256, 0, stream>>>(h2s, row_ptr, col, dinv, b2, z2, N);

    // decoder (4 edges/wave)
    k_dot<<<((long)((L + 3) / 4) * 64 + TPB - 1) / TPB, TPB, 0, stream>>>(z2, es, ed, out, L);
}